// Round 9
// baseline (638.047 us; speedup 1.0000x reference)
//
#include <hip/hip_runtime.h>
#include <stdint.h>

#define NG 256      // num networks
#define KF 256      // IN_F
#define OF 256      // OUT_F
#define RT 128      // rows per tile-iteration (8 waves x 16 rows)
#define NTH 512     // 8 waves

using f32x4  = __attribute__((ext_vector_type(4))) float;
using bf16x8 = __attribute__((ext_vector_type(8))) __bf16;
using u16x8  = __attribute__((ext_vector_type(8))) unsigned short;

__device__ __forceinline__ unsigned short f2bf(float f) {
  unsigned u = __builtin_bit_cast(unsigned, f);
  u += 0x7fffu + ((u >> 16) & 1u);   // round-to-nearest-even
  return (unsigned short)(u >> 16);
}

// ---------------- offsets scan (1 block, 256 threads) ----------------
__global__ void scan_kernel(const int* __restrict__ counts, int* __restrict__ offs) {
  __shared__ int s[NG];
  int t = threadIdx.x;
  s[t] = counts[t];
  __syncthreads();
  #pragma unroll
  for (int d = 1; d < NG; d <<= 1) {
    int u = (t >= d) ? s[t - d] : 0;
    __syncthreads();
    s[t] += u;
    __syncthreads();
  }
  if (t == 0) offs[0] = 0;
  offs[t + 1] = s[t];
}

// ---------------- persistent per-group GEMM ----------------
// Grid = 256 blocks (one per group, ~1 per CU). Stage the group's full W
// (128KB bf16, swizzled) + bias into LDS ONCE via regs+ds_write+__syncthreads
// (lgkm path - no global_load_lds DMA race class, R7 lesson). Then loop over
// row-tiles (128 rows/iter) with NO barriers: cvt A(t) -> prefetch A(t+1) ->
// 128 {ds_read_b128 + MFMA} -> guarded f32x4 stores. Ws is read-only after
// staging, so waves free-run and the load/store streams never drain.
// R8 lesson: re-staging W per 256-row block + phase lockstep = 1.8 TB/s cap.
//
// LDS layout (verified conflict-free since R6): slot16 sl = kt*1024 + o*4 + sp
// holds W[g][o][kt*32 + (sp^((o>>1)&3))*8 .. +8] as bf16x8.
// Read: o = n*16+lrow, sp = slot = lk^((lrow>>1)&3)  =>  k-range kt*32+lk*8.
__global__ __launch_bounds__(NTH, 2)
void gemm_kernel(const float* __restrict__ x,
                 const float* __restrict__ wf32,
                 const float* __restrict__ bias,
                 const int* __restrict__ offs,
                 float* __restrict__ out)
{
  __shared__ __align__(16) unsigned short Ws[8 * 8192];   // 128 KB: full W image
  __shared__ __align__(16) float Bias[OF];                // 1 KB

  const int g   = blockIdx.x;
  const int r0  = offs[g];
  const int cnt = offs[g + 1] - r0;
  if (cnt <= 0) return;

  const int tid  = threadIdx.x;
  const int lane = tid & 63;
  const int w    = tid >> 6;       // wave 0..7
  const int lrow = lane & 15;
  const int lk   = lane >> 4;      // 0..3
  const int slot = lk ^ ((lrow >> 1) & 3);

  // ---- prefetch A tile 0 (overlaps W staging below) ----
  f32x4 af[16];
  {
    int ar = min(w * 16 + lrow, cnt - 1);
    const float* ap = x + (size_t)(r0 + ar) * KF + lk * 8;
    #pragma unroll
    for (int kt = 0; kt < 8; ++kt) {
      af[kt * 2]     = *(const f32x4*)(ap + kt * 32);
      af[kt * 2 + 1] = *(const f32x4*)(ap + kt * 32 + 4);
    }
  }

  // ---- stage W (f32 -> bf16, swizzled) + bias via ds_write ----
  #pragma unroll
  for (int i = 0; i < 16; ++i) {
    int sl = i * 512 + tid;
    int kt = sl >> 10, o = (sl >> 2) & 255, sp = sl & 3;
    int s  = sp ^ ((o >> 1) & 3);
    const float* p = wf32 + (size_t)(g * 256 + o) * 256 + kt * 32 + s * 8;
    f32x4 a = *(const f32x4*)p;
    f32x4 b = *(const f32x4*)(p + 4);
    u16x8 r;
    r[0]=f2bf(a[0]); r[1]=f2bf(a[1]); r[2]=f2bf(a[2]); r[3]=f2bf(a[3]);
    r[4]=f2bf(b[0]); r[5]=f2bf(b[1]); r[6]=f2bf(b[2]); r[7]=f2bf(b[3]);
    *(u16x8*)((char*)Ws + (size_t)sl * 16) = r;
  }
  if (tid < OF) Bias[tid] = bias[g * OF + tid];

  __syncthreads();   // ds_writes published (lgkm); af may still be in flight (fine)

  const int nt = (cnt + RT - 1) / RT;

  for (int t = 0; t < nt; ++t) {
    // cvt A(t) -> bf16 frags (waits on af loads; frees af)
    bf16x8 xf[8];
    #pragma unroll
    for (int kt = 0; kt < 8; ++kt) {
      f32x4 lo = af[kt * 2], hi = af[kt * 2 + 1];
      u16x8 r;
      r[0]=f2bf(lo[0]); r[1]=f2bf(lo[1]); r[2]=f2bf(lo[2]); r[3]=f2bf(lo[3]);
      r[4]=f2bf(hi[0]); r[5]=f2bf(hi[1]); r[6]=f2bf(hi[2]); r[7]=f2bf(hi[3]);
      xf[kt] = __builtin_bit_cast(bf16x8, r);
    }

    // prefetch A(t+1): lands under this tile's compute
    if (t + 1 < nt) {
      int ar = min((t + 1) * RT + w * 16 + lrow, cnt - 1);
      const float* ap = x + (size_t)(r0 + ar) * KF + lk * 8;
      #pragma unroll
      for (int kt = 0; kt < 8; ++kt) {
        af[kt * 2]     = *(const f32x4*)(ap + kt * 32);
        af[kt * 2 + 1] = *(const f32x4*)(ap + kt * 32 + 4);
      }
    }

    // acc init with bias from LDS (broadcast reads, conflict-free)
    f32x4 acc[16];
    #pragma unroll
    for (int n = 0; n < 16; ++n)
      acc[n] = *(const f32x4*)&Bias[n * 16 + lk * 4];

    // 128 ds_read_b128 + 128 MFMA, no barriers
    #pragma unroll
    for (int kt = 0; kt < 8; ++kt) {
      #pragma unroll
      for (int n = 0; n < 16; ++n) {
        bf16x8 wf = *(const bf16x8*)&Ws[kt * 8192 + ((n * 16 + lrow) * 4 + slot) * 8];
        acc[n] = __builtin_amdgcn_mfma_f32_16x16x32_bf16(wf, xf[kt], acc[n], 0, 0, 0);
      }
    }

    // guarded f32x4 stores (D: lane holds out row=lrow, cols n*16+lk*4+j)
    int r = t * RT + w * 16 + lrow;
    if (r < cnt) {
      float* orow = out + (size_t)(r0 + r) * OF + lk * 4;
      #pragma unroll
      for (int n = 0; n < 16; ++n)
        *(f32x4*)&orow[n * 16] = acc[n];
    }
  }
}

extern "C" void kernel_launch(void* const* d_in, const int* in_sizes, int n_in,
                              void* d_out, int out_size, void* d_ws, size_t ws_size,
                              hipStream_t stream) {
  const float* weight = (const float*)d_in[0];
  const float* bias   = (const float*)d_in[1];
  const float* x      = (const float*)d_in[2];
  const int*   counts = (const int*)d_in[3];
  float* out = (float*)d_out;

  int* offs = (int*)d_ws;   // NG+1 ints

  scan_kernel<<<1, 256, 0, stream>>>(counts, offs);
  gemm_kernel<<<NG, NTH, 0, stream>>>(x, weight, bias, offs, out);
}

// Round 10
// 637.154 us; speedup vs baseline: 1.0014x; 1.0014x over previous
//
#include <hip/hip_runtime.h>
#include <stdint.h>

#define NG 256      // num networks
#define KF 256      // IN_F
#define OF 256      // OUT_F
#define RT 128      // rows per tile-iteration (8 waves x 16 rows)
#define NTH 512     // 8 waves

using f32x4  = __attribute__((ext_vector_type(4))) float;
using bf16x8 = __attribute__((ext_vector_type(8))) __bf16;
using u16x8  = __attribute__((ext_vector_type(8))) unsigned short;

__device__ __forceinline__ unsigned short f2bf(float f) {
  unsigned u = __builtin_bit_cast(unsigned, f);
  u += 0x7fffu + ((u >> 16) & 1u);   // round-to-nearest-even
  return (unsigned short)(u >> 16);
}

// ---------------- offsets scan (1 block, 256 threads) ----------------
__global__ void scan_kernel(const int* __restrict__ counts, int* __restrict__ offs) {
  __shared__ int s[NG];
  int t = threadIdx.x;
  s[t] = counts[t];
  __syncthreads();
  #pragma unroll
  for (int d = 1; d < NG; d <<= 1) {
    int u = (t >= d) ? s[t - d] : 0;
    __syncthreads();
    s[t] += u;
    __syncthreads();
  }
  if (t == 0) offs[0] = 0;
  offs[t + 1] = s[t];
}

// ---------------- persistent per-group GEMM ----------------
// Grid = 256 blocks (one per group, 1 per CU; 129KB LDS forces 1 anyway).
// Stage the group's full W (128KB bf16, swizzled) + bias into LDS ONCE via
// regs+ds_write+__syncthreads (lgkm path - no DMA race class, R7 lesson).
// Then loop over row-tiles (128 rows/iter) with NO barriers: cvt A(t) ->
// prefetch A(t+1) -> 128 {ds_read_b128 + MFMA} -> guarded f32x4 stores.
//
// LAUNCH_BOUNDS LESSON (R5/R6/R9 empirical): 2nd arg is CUDA-style MIN
// BLOCKS PER CU. (512,4)->64-reg cap (R5 spilled); (512,2)->128-reg cap
// (R9's ~180-reg live set spilled: +266MB scratch WRITE, +1GB FETCH).
// (512,1) -> 256-reg cap: af[16]+xf[8]+acc[16]+addr ~= 180 fits, NO spill.
//
// LDS layout (verified conflict-free since R6): slot16 sl = kt*1024 + o*4 + sp
// holds W[g][o][kt*32 + (sp^((o>>1)&3))*8 .. +8] as bf16x8.
// Read: o = n*16+lrow, sp = slot = lk^((lrow>>1)&3)  =>  k-range kt*32+lk*8.
__global__ __launch_bounds__(NTH, 1)
void gemm_kernel(const float* __restrict__ x,
                 const float* __restrict__ wf32,
                 const float* __restrict__ bias,
                 const int* __restrict__ offs,
                 float* __restrict__ out)
{
  __shared__ __align__(16) unsigned short Ws[8 * 8192];   // 128 KB: full W image
  __shared__ __align__(16) float Bias[OF];                // 1 KB

  const int g   = blockIdx.x;
  const int r0  = offs[g];
  const int cnt = offs[g + 1] - r0;
  if (cnt <= 0) return;

  const int tid  = threadIdx.x;
  const int lane = tid & 63;
  const int w    = tid >> 6;       // wave 0..7
  const int lrow = lane & 15;
  const int lk   = lane >> 4;      // 0..3
  const int slot = lk ^ ((lrow >> 1) & 3);

  // ---- prefetch A tile 0 (overlaps W staging below) ----
  f32x4 af[16];
  {
    int ar = min(w * 16 + lrow, cnt - 1);
    const float* ap = x + (size_t)(r0 + ar) * KF + lk * 8;
    #pragma unroll
    for (int kt = 0; kt < 8; ++kt) {
      af[kt * 2]     = *(const f32x4*)(ap + kt * 32);
      af[kt * 2 + 1] = *(const f32x4*)(ap + kt * 32 + 4);
    }
  }

  // ---- stage W (f32 -> bf16, swizzled) + bias via ds_write ----
  #pragma unroll
  for (int i = 0; i < 16; ++i) {
    int sl = i * 512 + tid;
    int kt = sl >> 10, o = (sl >> 2) & 255, sp = sl & 3;
    int s  = sp ^ ((o >> 1) & 3);
    const float* p = wf32 + (size_t)(g * 256 + o) * 256 + kt * 32 + s * 8;
    f32x4 a = *(const f32x4*)p;
    f32x4 b = *(const f32x4*)(p + 4);
    u16x8 r;
    r[0]=f2bf(a[0]); r[1]=f2bf(a[1]); r[2]=f2bf(a[2]); r[3]=f2bf(a[3]);
    r[4]=f2bf(b[0]); r[5]=f2bf(b[1]); r[6]=f2bf(b[2]); r[7]=f2bf(b[3]);
    *(u16x8*)((char*)Ws + (size_t)sl * 16) = r;
  }
  if (tid < OF) Bias[tid] = bias[g * OF + tid];

  __syncthreads();   // ds_writes published (lgkm); af may still be in flight (fine)

  const int nt = (cnt + RT - 1) / RT;

  for (int t = 0; t < nt; ++t) {
    // cvt A(t) -> bf16 frags (waits on af loads; frees af)
    bf16x8 xf[8];
    #pragma unroll
    for (int kt = 0; kt < 8; ++kt) {
      f32x4 lo = af[kt * 2], hi = af[kt * 2 + 1];
      u16x8 r;
      r[0]=f2bf(lo[0]); r[1]=f2bf(lo[1]); r[2]=f2bf(lo[2]); r[3]=f2bf(lo[3]);
      r[4]=f2bf(hi[0]); r[5]=f2bf(hi[1]); r[6]=f2bf(hi[2]); r[7]=f2bf(hi[3]);
      xf[kt] = __builtin_bit_cast(bf16x8, r);
    }

    // prefetch A(t+1): lands under this tile's compute
    if (t + 1 < nt) {
      int ar = min((t + 1) * RT + w * 16 + lrow, cnt - 1);
      const float* ap = x + (size_t)(r0 + ar) * KF + lk * 8;
      #pragma unroll
      for (int kt = 0; kt < 8; ++kt) {
        af[kt * 2]     = *(const f32x4*)(ap + kt * 32);
        af[kt * 2 + 1] = *(const f32x4*)(ap + kt * 32 + 4);
      }
    }

    // acc init with bias from LDS (broadcast reads, conflict-free)
    f32x4 acc[16];
    #pragma unroll
    for (int n = 0; n < 16; ++n)
      acc[n] = *(const f32x4*)&Bias[n * 16 + lk * 4];

    // 128 ds_read_b128 + 128 MFMA, no barriers
    #pragma unroll
    for (int kt = 0; kt < 8; ++kt) {
      #pragma unroll
      for (int n = 0; n < 16; ++n) {
        bf16x8 wf = *(const bf16x8*)&Ws[kt * 8192 + ((n * 16 + lrow) * 4 + slot) * 8];
        acc[n] = __builtin_amdgcn_mfma_f32_16x16x32_bf16(wf, xf[kt], acc[n], 0, 0, 0);
      }
    }

    // guarded f32x4 stores (D: lane holds out row=lrow, cols n*16+lk*4+j)
    int r = t * RT + w * 16 + lrow;
    if (r < cnt) {
      float* orow = out + (size_t)(r0 + r) * OF + lk * 4;
      #pragma unroll
      for (int n = 0; n < 16; ++n)
        *(f32x4*)&orow[n * 16] = acc[n];
    }
  }
}

extern "C" void kernel_launch(void* const* d_in, const int* in_sizes, int n_in,
                              void* d_out, int out_size, void* d_ws, size_t ws_size,
                              hipStream_t stream) {
  const float* weight = (const float*)d_in[0];
  const float* bias   = (const float*)d_in[1];
  const float* x      = (const float*)d_in[2];
  const int*   counts = (const int*)d_in[3];
  float* out = (float*)d_out;

  int* offs = (int*)d_ws;   // NG+1 ints

  scan_kernel<<<1, 256, 0, stream>>>(counts, offs);
  gemm_kernel<<<NG, NTH, 0, stream>>>(x, weight, bias, offs, out);
}